// Round 6
// baseline (83.019 us; speedup 1.0000x reference)
//
#include <hip/hip_runtime.h>
#include <math.h>

// Problem constants (fixed by reference)
constexpr int N_ = 4, P_ = 64, Z_ = 32, Y_ = 128, X_ = 128;
constexpr float EPSF = 1e-8f;
constexpr float INV2S2 = 0.125f;   // 1/(2*sigma^2), sigma = 2

// ws layout: kzyG[n][z][y][p] = exp(-((z-pz)^2+(y-py)^2)/8), 4*32*128*64
// floats = 4 MB, then part[512][64] block partials.
constexpr int KZY_ELEMS = N_ * Z_ * Y_ * P_;       // 1,048,576
constexpr int PART_OFF  = KZY_ELEMS;

// ---------------------------------------------------------------------------
// Table kernel: one float4 (4 consecutive p) per thread. 1024 blocks x 256.
// Writes coalesced; pts reads are L2-broadcast. ~1M exps across 256 CUs.
// ---------------------------------------------------------------------------
__global__ __launch_bounds__(256) void k_table(const float* __restrict__ pts,
                                               float* __restrict__ kzyG) {
    const int idx = blockIdx.x * 256 + threadIdx.x;   // 262144 float4s
    const int rowg = idx >> 4;          // (n,z,y): 0..16383
    const int p0 = (idx & 15) * 4;
    const int n = rowg >> 12;
    const float z = (float)((rowg >> 7) & 31);
    const float y = (float)(rowg & 127);
    const float* pn = pts + (size_t)(n * P_ + p0) * 3;
    float4 r;
    {
        float dz = z - pn[0], dy = y - pn[1];
        r.x = __expf(-(dz * dz + dy * dy) * INV2S2);
    }
    {
        float dz = z - pn[3], dy = y - pn[4];
        r.y = __expf(-(dz * dz + dy * dy) * INV2S2);
    }
    {
        float dz = z - pn[6], dy = y - pn[7];
        r.z = __expf(-(dz * dz + dy * dy) * INV2S2);
    }
    {
        float dz = z - pn[9], dy = y - pn[10];
        r.w = __expf(-(dz * dz + dy * dy) * INV2S2);
    }
    ((float4*)kzyG)[idx] = r;
}

// ---------------------------------------------------------------------------
// Main kernel. Grid: 512 blocks = (n, z, y-half, x-half); 256 thr = 4 waves.
// Each wave owns one y-row per pass (16 passes), each thread one x-column.
// The wave-uniform kzy row is read from GLOBAL via broadcast dwordx4 (VMEM
// pipe, L1/L2-hot, one request per instr since all 64 lanes share the
// address) instead of LDS: R5 proved DS ops at 8 waves/CU cost ~6 cyc each
// serialized per CU; the old 2048 b128/CU was ~10 us of DS time. Kernel LDS
// use is now just ptsn + the tiny epilogue buffer.
// kkx[p]=krow*kxr once/pass; denom = 4-way partial sum; macc += kkx*w.
// VGPR ~210 (kxr[64]+macc[64]+kkx[64]) -> __launch_bounds__(256,2).
// ---------------------------------------------------------------------------
__global__ __launch_bounds__(256, 2) void k_fused(const float* __restrict__ logits,
                                                  const float* __restrict__ pts,
                                                  const float* __restrict__ kzyG,
                                                  float* __restrict__ part) {
    const int b = blockIdx.x;          // 512 blocks: [n:2][z:5][yh:1][xh:1]
    const int n  = b >> 7;
    const int z  = (b >> 2) & 31;
    const int y0 = ((b >> 1) & 1) * 64;
    const int x0 = (b & 1) * 64;

    const int tid = threadIdx.x;
    const int lane = tid & 63;
    const int wid = tid >> 6;

    __shared__ float ptsn[192];        // pts[n] = [64][3]
    __shared__ float wsum[4][64];

    if (tid < 192) ptsn[tid] = pts[n * 192 + tid];
    __syncthreads();

    const int x = x0 + lane;
    float kxr[64], macc[64];
    #pragma unroll
    for (int p = 0; p < 64; ++p) {
        float dx = (float)x - ptsn[p * 3 + 2];
        kxr[p] = __expf(-dx * dx * INV2S2);   // ptsn stride-3: 2-way alias, free
        macc[p] = 0.0f;
    }

    const float* lbase = logits + (size_t)((n * Z_ + z) * Y_ + y0) * X_ + x;
    // kzy rows for this block: kzyG[((n*Z+z)*Y + y0+row)*64 + ...]
    const float4* krow0 = (const float4*)(kzyG + (size_t)((n * Z_ + z) * Y_ + y0) * 64);

    float lg = lbase[wid * X_];        // prefetch pass-0 logit
    #pragma unroll 1
    for (int pass = 0; pass < 16; ++pass) {
        const int row = pass * 4 + wid;           // wave-uniform row
        float lg_next = 0.0f;
        if (pass < 15) lg_next = lbase[(row + 4) * X_];   // prefetch next pass

        const float4* kr = krow0 + row * 16;      // broadcast dwordx4 loads
        float kkx[64];
        float d0 = 0.f, d1 = 0.f, d2 = 0.f, d3 = 0.f;
        #pragma unroll
        for (int q = 0; q < 16; ++q) {
            const float4 k4 = kr[q];
            kkx[4*q+0] = k4.x * kxr[4*q+0]; d0 += kkx[4*q+0];
            kkx[4*q+1] = k4.y * kxr[4*q+1]; d1 += kkx[4*q+1];
            kkx[4*q+2] = k4.z * kxr[4*q+2]; d2 += kkx[4*q+2];
            kkx[4*q+3] = k4.w * kxr[4*q+3]; d3 += kkx[4*q+3];
        }
        const float denom = (d0 + d1) + (d2 + d3);
        // w = sigmoid(lg) / max(denom, EPS): one fp32 divide
        const float w = 1.0f / ((1.0f + __expf(-lg)) * fmaxf(denom, EPSF));

        #pragma unroll
        for (int p = 0; p < 64; ++p) macc[p] = fmaf(kkx[p], w, macc[p]);
        lg = lg_next;
    }

    // Butterfly array-halving reduction (R5 win): 6 stages, 63 shuffles per
    // thread; lane l ends holding the wave total for p == l.
    float* v = macc;
#define RED_STAGE(D)                                              \
    {                                                             \
        const bool hi = (lane & (D)) != 0;                        \
        _Pragma("unroll")                                         \
        for (int i = 0; i < (D); ++i) {                           \
            float mine = hi ? v[i + (D)] : v[i];                  \
            float send = hi ? v[i] : v[i + (D)];                  \
            float got = __shfl_xor(send, (D), 64);                \
            v[i] = mine + got;                                    \
        }                                                         \
    }
    RED_STAGE(32) RED_STAGE(16) RED_STAGE(8)
    RED_STAGE(4)  RED_STAGE(2)  RED_STAGE(1)
#undef RED_STAGE
    wsum[wid][lane] = v[0];
    __syncthreads();
    if (tid < 64) {
        float s = (wsum[0][tid] + wsum[1][tid]) + (wsum[2][tid] + wsum[3][tid]);
        part[b * 64 + tid] = s;        // private slot: plain store, no atomic
    }
}

// ---------------------------------------------------------------------------
// Finish kernel: m[n][p] = sum of that n's 128 block-partials, then
// loss = mean_{n,p} -log(max(m, EPS)). 1 block x 1024 threads, 4-way split
// of the partial sum per (n,p), combined in LDS.
// ---------------------------------------------------------------------------
__global__ __launch_bounds__(1024) void k_finish(const float* __restrict__ part,
                                                 float* __restrict__ out) {
    const int t = threadIdx.x;
    const int pair = t & 255;          // (n,p): n = pair>>6, p = pair&63
    const int quarter = t >> 8;        // which 32-block slice
    const int n = pair >> 6, p = pair & 63;

    const float* base = part + (size_t)(n * 128 + quarter * 32) * 64 + p;
    float s0 = 0.f, s1 = 0.f, s2 = 0.f, s3 = 0.f;
    #pragma unroll 2
    for (int j = 0; j < 32; j += 4) {  // independent accumulators
        s0 += base[(j + 0) * 64];
        s1 += base[(j + 1) * 64];
        s2 += base[(j + 2) * 64];
        s3 += base[(j + 3) * 64];
    }
    __shared__ float red[4][256];
    red[quarter][pair] = (s0 + s1) + (s2 + s3);
    __syncthreads();

    if (t < 256) {
        const float m = (red[0][t] + red[1][t]) + (red[2][t] + red[3][t]);
        float l = -logf(fmaxf(m, EPSF));
        #pragma unroll
        for (int off = 32; off > 0; off >>= 1) l += __shfl_xor(l, off, 64);
        __shared__ float red2[4];
        if ((t & 63) == 0) red2[t >> 6] = l;
        __syncthreads();
        if (t == 0) out[0] = (red2[0] + red2[1] + red2[2] + red2[3]) * (1.0f / 256.0f);
    }
}

extern "C" void kernel_launch(void* const* d_in, const int* in_sizes, int n_in,
                              void* d_out, int out_size, void* d_ws, size_t ws_size,
                              hipStream_t stream) {
    const float* logits = (const float*)d_in[0];  // [4,1,32,128,128] fp32
    const float* pts    = (const float*)d_in[1];  // [4,64,3] fp32
    float* kzyG = (float*)d_ws;                   // 4 MB table
    float* part = (float*)d_ws + PART_OFF;        // 512*64 floats
    float* out  = (float*)d_out;                  // scalar fp32

    k_table<<<dim3(1024), dim3(256), 0, stream>>>(pts, kzyG);
    k_fused<<<dim3(512), dim3(256), 0, stream>>>(logits, pts, kzyG, part);
    k_finish<<<dim3(1), dim3(1024), 0, stream>>>(part, out);
}

// Round 7
// 76.708 us; speedup vs baseline: 1.0823x; 1.0823x over previous
//
#include <hip/hip_runtime.h>
#include <math.h>

// Problem constants (fixed by reference)
constexpr int N_ = 4, P_ = 64, Z_ = 32, Y_ = 128, X_ = 128;
constexpr float EPSF = 1e-8f;
constexpr float INV2S2 = 0.125f;   // 1/(2*sigma^2), sigma = 2

// ---------------------------------------------------------------------------
// Fused kernel (R5 structure + 2 x-columns/thread).
// Grid: 512 blocks = (n, z, y-quarter); 256 threads = 4 waves. Each block
// covers 32 y-rows x full 128 x. Each wave owns one y-row per pass (8
// passes); each thread owns xA = lane and xB = lane+64 -> TWO independent
// denom/w latency chains per thread, 8 waves/CU => latency-hiding product 16
// (2x R5; R2~R3 showed product, not occupancy alone, is what matters).
//
// kzy[row][p] tile in LDS (2048 exps, 8/thread); kxA/kxB in VGPRs (128
// exps/thread). Product of separable exps == reference single exp to ~ulp
// above the 1e-8 denom floor. macc[p] shared by both columns:
//   macc[p] += k*(kxA[p]*wA + kxB[p]*wB)   (2.5 VALU/voxel vs 3 in R5)
// kzy row re-read in the macc loop (broadcast b128; kkx[] dropped to keep
// VGPR state ~220 <= 256 cap at __launch_bounds__(256,2)).
//
// Per-block partial written to a PRIVATE slot: full overwrite, no pre-zero
// (ws is 0xAA-poisoned), no atomics.
// ---------------------------------------------------------------------------
__global__ __launch_bounds__(256, 2) void k_fused(const float* __restrict__ logits,
                                                  const float* __restrict__ pts,
                                                  float* __restrict__ part) {
    const int b = blockIdx.x;          // 512 blocks: [n:2][z:5][yq:2]
    const int n  = b >> 7;
    const int z  = (b >> 2) & 31;
    const int y0 = (b & 3) * 32;

    const int tid = threadIdx.x;
    const int lane = tid & 63;
    const int wid = tid >> 6;

    __shared__ float ptsn[192];        // pts[n] = [64][3]
    __shared__ float kzy[32 * 64];     // [row][p], 8 KB
    __shared__ float wsum[4][64];

    if (tid < 192) ptsn[tid] = pts[n * 192 + tid];
    __syncthreads();

    // kzy tile: 2048 exps / 256 threads = 8 per thread.
    for (int i = tid; i < 32 * 64; i += 256) {
        int row = i >> 6, p = i & 63;  // ptsn stride-3 reads: 2-way alias, free
        float dz = (float)z - ptsn[p * 3 + 0];
        float dy = (float)(y0 + row) - ptsn[p * 3 + 1];
        kzy[i] = __expf(-(dz * dz + dy * dy) * INV2S2);
    }

    float kxA[64], kxB[64], macc[64];
    #pragma unroll
    for (int p = 0; p < 64; ++p) {
        float pxv = ptsn[p * 3 + 2];
        float dxA = (float)lane - pxv;
        float dxB = (float)(lane + 64) - pxv;
        kxA[p] = __expf(-dxA * dxA * INV2S2);
        kxB[p] = __expf(-dxB * dxB * INV2S2);
        macc[p] = 0.0f;
    }
    __syncthreads();

    const float* lbase = logits + (size_t)((n * Z_ + z) * Y_ + y0) * X_ + lane;

    float lgA = lbase[wid * X_];             // prefetch pass-0 logits
    float lgB = lbase[wid * X_ + 64];
    #pragma unroll 1
    for (int pass = 0; pass < 8; ++pass) {
        const int row = pass * 4 + wid;      // wave-uniform row
        float lgA_n = 0.0f, lgB_n = 0.0f;
        if (pass < 7) {                      // prefetch next pass
            lgA_n = lbase[(row + 4) * X_];
            lgB_n = lbase[(row + 4) * X_ + 64];
        }

        const float4* kr = (const float4*)(&kzy[row * 64]);
        float a0 = 0.f, a1 = 0.f, a2 = 0.f, a3 = 0.f;   // denom chains, xA
        float b0 = 0.f, b1 = 0.f, b2 = 0.f, b3 = 0.f;   // denom chains, xB
        #pragma unroll
        for (int q = 0; q < 16; ++q) {
            const float4 k4 = kr[q];                    // broadcast b128
            a0 = fmaf(k4.x, kxA[4*q+0], a0); b0 = fmaf(k4.x, kxB[4*q+0], b0);
            a1 = fmaf(k4.y, kxA[4*q+1], a1); b1 = fmaf(k4.y, kxB[4*q+1], b1);
            a2 = fmaf(k4.z, kxA[4*q+2], a2); b2 = fmaf(k4.z, kxB[4*q+2], b2);
            a3 = fmaf(k4.w, kxA[4*q+3], a3); b3 = fmaf(k4.w, kxB[4*q+3], b3);
        }
        const float dA = (a0 + a1) + (a2 + a3);
        const float dB = (b0 + b1) + (b2 + b3);
        // w = sigmoid(lg)/max(d,EPS) = 1/((1+e^-lg)*max(d,EPS)): 1 divide/voxel
        const float wA = 1.0f / ((1.0f + __expf(-lgA)) * fmaxf(dA, EPSF));
        const float wB = 1.0f / ((1.0f + __expf(-lgB)) * fmaxf(dB, EPSF));

        #pragma unroll
        for (int q = 0; q < 16; ++q) {
            const float4 k4 = kr[q];                    // re-read (broadcast)
            macc[4*q+0] = fmaf(k4.x, fmaf(kxB[4*q+0], wB, kxA[4*q+0] * wA), macc[4*q+0]);
            macc[4*q+1] = fmaf(k4.y, fmaf(kxB[4*q+1], wB, kxA[4*q+1] * wA), macc[4*q+1]);
            macc[4*q+2] = fmaf(k4.z, fmaf(kxB[4*q+2], wB, kxA[4*q+2] * wA), macc[4*q+2]);
            macc[4*q+3] = fmaf(k4.w, fmaf(kxB[4*q+3], wB, kxA[4*q+3] * wA), macc[4*q+3]);
        }
        lgA = lgA_n; lgB = lgB_n;
    }

    // Butterfly array-halving reduction (R5 win): 6 stages, 63 shuffles per
    // thread; lane l ends holding the wave total for p == l.
    float* v = macc;
#define RED_STAGE(D)                                              \
    {                                                             \
        const bool hi = (lane & (D)) != 0;                        \
        _Pragma("unroll")                                         \
        for (int i = 0; i < (D); ++i) {                           \
            float mine = hi ? v[i + (D)] : v[i];                  \
            float send = hi ? v[i] : v[i + (D)];                  \
            float got = __shfl_xor(send, (D), 64);                \
            v[i] = mine + got;                                    \
        }                                                         \
    }
    RED_STAGE(32) RED_STAGE(16) RED_STAGE(8)
    RED_STAGE(4)  RED_STAGE(2)  RED_STAGE(1)
#undef RED_STAGE
    wsum[wid][lane] = v[0];
    __syncthreads();
    if (tid < 64) {
        float s = (wsum[0][tid] + wsum[1][tid]) + (wsum[2][tid] + wsum[3][tid]);
        part[b * 64 + tid] = s;        // private slot: plain store, no atomic
    }
}

// ---------------------------------------------------------------------------
// Finish kernel: m[n][p] = sum of that n's 128 block-partials, then
// loss = mean_{n,p} -log(max(m, EPS)). 1 block x 1024 threads, 4-way split
// of the partial sum per (n,p), combined in LDS.
// ---------------------------------------------------------------------------
__global__ __launch_bounds__(1024) void k_finish(const float* __restrict__ part,
                                                 float* __restrict__ out) {
    const int t = threadIdx.x;
    const int pair = t & 255;          // (n,p): n = pair>>6, p = pair&63
    const int quarter = t >> 8;        // which 32-block slice
    const int n = pair >> 6, p = pair & 63;

    const float* base = part + (size_t)(n * 128 + quarter * 32) * 64 + p;
    float s0 = 0.f, s1 = 0.f, s2 = 0.f, s3 = 0.f;
    #pragma unroll 2
    for (int j = 0; j < 32; j += 4) {  // independent accumulators
        s0 += base[(j + 0) * 64];
        s1 += base[(j + 1) * 64];
        s2 += base[(j + 2) * 64];
        s3 += base[(j + 3) * 64];
    }
    __shared__ float red[4][256];
    red[quarter][pair] = (s0 + s1) + (s2 + s3);
    __syncthreads();

    if (t < 256) {
        const float m = (red[0][t] + red[1][t]) + (red[2][t] + red[3][t]);
        float l = -logf(fmaxf(m, EPSF));
        #pragma unroll
        for (int off = 32; off > 0; off >>= 1) l += __shfl_xor(l, off, 64);
        __shared__ float red2[4];
        if ((t & 63) == 0) red2[t >> 6] = l;
        __syncthreads();
        if (t == 0) out[0] = (red2[0] + red2[1] + red2[2] + red2[3]) * (1.0f / 256.0f);
    }
}

extern "C" void kernel_launch(void* const* d_in, const int* in_sizes, int n_in,
                              void* d_out, int out_size, void* d_ws, size_t ws_size,
                              hipStream_t stream) {
    const float* logits = (const float*)d_in[0];  // [4,1,32,128,128] fp32
    const float* pts    = (const float*)d_in[1];  // [4,64,3] fp32
    float* part = (float*)d_ws;                   // 512*64 floats = 128 KB
    float* out  = (float*)d_out;                  // scalar fp32

    k_fused<<<dim3(512), dim3(256), 0, stream>>>(logits, pts, part);
    k_finish<<<dim3(1), dim3(1024), 0, stream>>>(part, out);
}